// Round 1
// baseline (65.308 us; speedup 1.0000x reference)
//
#include <hip/hip_runtime.h>

// Problem constants (from reference)
#define BATCH 64
#define LEXPR 8192
#define FSUB  100
#define VOCAB 64
#define NPOS  (LEXPR + 1)   // 8193 valid conv positions
#define TPB   1024

__global__ __launch_bounds__(TPB)
void Finder_66640712565346_kernel(const int* __restrict__ expr,
                                  const int* __restrict__ sub,
                                  float* __restrict__ out) {
    // LDS: per-vocab bitmask of sub positions, score accumulator, reduction scratch
    __shared__ unsigned int mask[VOCAB][4];   // 100 bits per vocab value
    __shared__ unsigned int score[NPOS];      // 32.8 KB
    __shared__ unsigned int red[TPB];

    const int b   = blockIdx.x;
    const int tid = threadIdx.x;

    // Zero masks and score array
    for (int i = tid; i < VOCAB * 4; i += TPB) ((unsigned int*)mask)[i] = 0u;
    for (int i = tid; i < NPOS; i += TPB) score[i] = 0u;
    __syncthreads();

    // Build per-vocab bitmasks from sub_expression; PAD (0) contributes nothing.
    if (tid < FSUB) {
        int v = sub[b * FSUB + tid];
        if (v != 0) atomicOr(&mask[v][tid >> 5], 1u << (tid & 31));
    }
    __syncthreads();

    // Scatter: for each expression index j, every sub position f with sub[f]==expr[j]
    // contributes score[j-f]++ (position p = j-f must be >= 0; p <= 8191 < NPOS always).
    const int* erow = expr + b * LEXPR;
    for (int j = tid; j < LEXPR; j += TPB) {
        int v = erow[j];
        unsigned int m0 = mask[v][0];
        unsigned int m1 = mask[v][1];
        unsigned int m2 = mask[v][2];
        unsigned int m3 = mask[v][3];
        while (m0) { int f =      __builtin_ctz(m0); m0 &= m0 - 1u; int p = j - f; if (p >= 0) atomicAdd(&score[p], 1u); }
        while (m1) { int f = 32 + __builtin_ctz(m1); m1 &= m1 - 1u; int p = j - f; if (p >= 0) atomicAdd(&score[p], 1u); }
        while (m2) { int f = 64 + __builtin_ctz(m2); m2 &= m2 - 1u; int p = j - f; if (p >= 0) atomicAdd(&score[p], 1u); }
        while (m3) { int f = 96 + __builtin_ctz(m3); m3 &= m3 - 1u; int p = j - f; if (p >= 0) atomicAdd(&score[p], 1u); }
    }
    __syncthreads();

    // First-max argmax via packed key: (score << 14) | (16383 - p).
    // Max key => max score, ties => smallest p (matches jnp.argmax first-occurrence).
    // score <= 100 (7 bits), p <= 8192 (14 bits) -> fits u32.
    unsigned int best = 0u;
    for (int p = tid; p < NPOS; p += TPB) {
        unsigned int k = (score[p] << 14) | (16383u - (unsigned int)p);
        if (k > best) best = k;
    }
    red[tid] = best;
    __syncthreads();
    for (int s = TPB / 2; s > 0; s >>= 1) {
        if (tid < s) {
            unsigned int a = red[tid + s];
            if (a > red[tid]) red[tid] = a;
        }
        __syncthreads();
    }
    if (tid == 0) {
        unsigned int k = red[0];
        out[b]         = (float)(16383u - (k & 16383u));  // position
        out[BATCH + b] = (float)(k >> 14);                // max score
    }
}

extern "C" void kernel_launch(void* const* d_in, const int* in_sizes, int n_in,
                              void* d_out, int out_size, void* d_ws, size_t ws_size,
                              hipStream_t stream) {
    const int* expr = (const int*)d_in[0];  // [64, 8192] int32
    const int* sub  = (const int*)d_in[1];  // [64, 100] int32
    float* out = (float*)d_out;             // [64] positions ++ [64] max scores

    Finder_66640712565346_kernel<<<BATCH, TPB, 0, stream>>>(expr, sub, out);
}